// Round 1
// 685.005 us; speedup vs baseline: 1.0039x; 1.0039x over previous
//
#include <hip/hip_runtime.h>

#define MEM_LEN 131072
#define IN_DIM 256
#define OUT_DIM 512
#define BETA 1.0f

// 16-byte vector with 4-byte alignment: lets the compiler emit an unaligned
// contiguous dwordx4 store (or 4 contiguous dword stores) into the +1-float
// shifted output region. Either lowering is fully coalesced per instruction,
// unlike the previous stride-16B dword scatter.
typedef float float4u __attribute__((vector_size(16), aligned(4)));

// ws layout (floats): [0..511] = enc (log_softmax output), [512] = loss bits (uint)

__global__ __launch_bounds__(512) void k_encode(
    const float* __restrict__ x, const float* __restrict__ W,
    const float* __restrict__ b, const float* __restrict__ mean,
    const float* __restrict__ stdv, float* __restrict__ ws)
{
    __shared__ float s_new[IN_DIM];
    __shared__ float s_wred[8];
    __shared__ float s_bcast;
    const int tid = threadIdx.x;
    const int lane = tid & 63;
    const int wave = tid >> 6;

    if (tid < IN_DIM) {
        float sd = stdv[tid];
        s_new[tid] = (sd == 0.0f) ? 0.0f : (x[tid] - mean[tid]) / sd;
    }
    __syncthreads();

    // z_j for j = tid (coalesced W reads across the wave)
    float z = b[tid];
    #pragma unroll 8
    for (int k = 0; k < IN_DIM; ++k)
        z = fmaf(s_new[k], W[k * OUT_DIM + tid], z);

    // block max
    float m = z;
    #pragma unroll
    for (int off = 32; off > 0; off >>= 1)
        m = fmaxf(m, __shfl_down(m, off, 64));
    if (lane == 0) s_wred[wave] = m;
    __syncthreads();
    if (tid == 0) {
        float mm = s_wred[0];
        for (int w = 1; w < 8; ++w) mm = fmaxf(mm, s_wred[w]);
        s_bcast = mm;
    }
    __syncthreads();
    const float zmax = s_bcast;

    // block sum of exp(z - zmax)
    float e = expf(z - zmax);
    float ssum = e;
    #pragma unroll
    for (int off = 32; off > 0; off >>= 1)
        ssum += __shfl_down(ssum, off, 64);
    __syncthreads();              // everyone has read s_bcast; safe to reuse LDS
    if (lane == 0) s_wred[wave] = ssum;
    __syncthreads();
    if (tid == 0) {
        float tot = 0.0f;
        for (int w = 0; w < 8; ++w) tot += s_wred[w];
        s_bcast = logf(tot);
        ((unsigned int*)ws)[512] = 0x7F800000u;   // +inf bits: init loss slot
    }
    __syncthreads();
    const float lse = s_bcast;

    ws[tid] = z - zmax - lse;     // enc_j
}

__global__ __launch_bounds__(256) void k_dist_copy(
    const float* __restrict__ memory, const float* __restrict__ mem_data,
    float* __restrict__ out, const float* __restrict__ ws)
{
    __shared__ alignas(16) float s_enc[OUT_DIM];
    __shared__ float s_min[4];
    const int tid = threadIdx.x;
    const int lane = tid & 63;
    const int wave = tid >> 6;

    s_enc[tid] = ws[tid];
    s_enc[256 + tid] = ws[256 + tid];
    __syncthreads();

    const float4 e0 = ((const float4*)s_enc)[lane];
    const float4 e1 = ((const float4*)s_enc)[64 + lane];

    const int gwave = blockIdx.x * 4 + wave;
    const int n_waves = gridDim.x * 4;

    float wmin = INFINITY;
    float* const out_mem = out + 1;

    for (int r = gwave; r < MEM_LEN; r += n_waves) {
        const float4* src = (const float4*)(memory + (size_t)r * OUT_DIM);
        const float4 a0 = src[lane];
        const float4 a1 = src[64 + lane];

        float s = fabsf(a0.x - e0.x) + fabsf(a0.y - e0.y)
                + fabsf(a0.z - e0.z) + fabsf(a0.w - e0.w)
                + fabsf(a1.x - e1.x) + fabsf(a1.y - e1.y)
                + fabsf(a1.z - e1.z) + fabsf(a1.w - e1.w);

        // fused copy to output: contiguous (unaligned) 16B store per lane
        float* dst = out_mem + (size_t)r * OUT_DIM;
        float4u t0 = {a0.x, a0.y, a0.z, a0.w};
        float4u t1 = {a1.x, a1.y, a1.z, a1.w};
        *(float4u*)(dst + 4 * lane)       = t0;
        *(float4u*)(dst + 256 + 4 * lane) = t1;

        #pragma unroll
        for (int off = 32; off > 0; off >>= 1)
            s += __shfl_down(s, off, 64);
        if (lane == 0) wmin = fminf(wmin, s);
    }

    if (lane == 0) s_min[wave] = wmin;
    __syncthreads();
    if (tid == 0) {
        float bm = fminf(fminf(s_min[0], s_min[1]), fminf(s_min[2], s_min[3]));
        atomicMin((unsigned int*)ws + 512, __float_as_uint(bm));
    }

    // mem_data copy (grid-stride, float4 loads, contiguous unaligned 16B stores)
    const size_t total4 = (size_t)MEM_LEN * IN_DIM / 4;
    const size_t stride = (size_t)gridDim.x * 256;
    float* const out_md = out + 1 + (size_t)MEM_LEN * OUT_DIM;
    const float4* src4 = (const float4*)mem_data;
    for (size_t i = (size_t)blockIdx.x * 256 + tid; i < total4; i += stride) {
        const float4 v = src4[i];
        float4u t = {v.x, v.y, v.z, v.w};
        *(float4u*)(out_md + i * 4) = t;
    }
}

__global__ __launch_bounds__(512) void k_finalize(
    const float* __restrict__ x, const int* __restrict__ count,
    float* __restrict__ out, const float* __restrict__ ws)
{
    const int tid = threadIdx.x;
    const float loss = __uint_as_float(((const unsigned int*)ws)[512]);
    if (tid == 0) out[0] = loss;
    if (loss <= BETA) {
        int pos = count[0] % MEM_LEN;
        if (pos < 0) pos += MEM_LEN;
        out[1 + (size_t)pos * OUT_DIM + tid] = ws[tid];
        if (tid < IN_DIM)
            out[1 + (size_t)MEM_LEN * OUT_DIM + (size_t)pos * IN_DIM + tid] = x[tid];
    }
}

extern "C" void kernel_launch(void* const* d_in, const int* in_sizes, int n_in,
                              void* d_out, int out_size, void* d_ws, size_t ws_size,
                              hipStream_t stream) {
    const float* x        = (const float*)d_in[0];
    const float* W_enc    = (const float*)d_in[1];
    const float* b_enc    = (const float*)d_in[2];
    const float* memory   = (const float*)d_in[3];
    const float* mem_data = (const float*)d_in[4];
    const float* mean     = (const float*)d_in[5];
    const float* stdv     = (const float*)d_in[6];
    const int*   count    = (const int*)d_in[7];
    float* out = (float*)d_out;
    float* ws  = (float*)d_ws;

    k_encode<<<1, 512, 0, stream>>>(x, W_enc, b_enc, mean, stdv, ws);
    k_dist_copy<<<2048, 256, 0, stream>>>(memory, mem_data, out, ws);
    k_finalize<<<1, 512, 0, stream>>>(x, count, out, ws);
}

// Round 2
// 661.708 us; speedup vs baseline: 1.0392x; 1.0352x over previous
//
#include <hip/hip_runtime.h>

#define MEM_LEN 131072
#define IN_DIM 256
#define OUT_DIM 512
#define BETA 1.0f
#define NSLICE 16
#define KSLICE (IN_DIM / NSLICE)   // 16 k-rows of W per slice block

// 16B vectors: v4 = aligned(16) for loads; v4u = aligned(4) so the compiler
// emits contiguous unaligned stores into the +1-float-shifted output region.
typedef float v4  __attribute__((vector_size(16)));
typedef float v4u __attribute__((vector_size(16), aligned(4)));

// ws layout (floats):
//   [0..511]                      enc (log_softmax output)
//   [512]                         loss bits (uint, atomicMin)
//   [1024 .. 1024+NSLICE*512)     k-slice partial dot products

__global__ __launch_bounds__(512) void k_enc1(
    const float* __restrict__ x, const float* __restrict__ W,
    const float* __restrict__ mean, const float* __restrict__ stdv,
    float* __restrict__ ws)
{
    __shared__ float s_new[KSLICE];
    const int tid = threadIdx.x;
    const int b = blockIdx.x;
    const int k0 = b * KSLICE;

    if (tid < KSLICE) {
        const int k = k0 + tid;
        const float sd = stdv[k];
        s_new[tid] = (sd == 0.0f) ? 0.0f : (x[k] - mean[k]) / sd;
    }
    __syncthreads();

    float acc = 0.0f;
    #pragma unroll
    for (int kk = 0; kk < KSLICE; ++kk)
        acc = fmaf(s_new[kk], W[(size_t)(k0 + kk) * OUT_DIM + tid], acc);
    ws[1024 + b * OUT_DIM + tid] = acc;
}

__global__ __launch_bounds__(512) void k_enc2(
    const float* __restrict__ bias, float* __restrict__ ws)
{
    __shared__ float s_wred[8];
    __shared__ float s_bcast;
    const int tid = threadIdx.x;
    const int lane = tid & 63;
    const int wave = tid >> 6;

    float z = bias[tid];
    #pragma unroll
    for (int s = 0; s < NSLICE; ++s)
        z += ws[1024 + s * OUT_DIM + tid];

    // block max
    float m = z;
    #pragma unroll
    for (int off = 32; off > 0; off >>= 1)
        m = fmaxf(m, __shfl_down(m, off, 64));
    if (lane == 0) s_wred[wave] = m;
    __syncthreads();
    if (tid == 0) {
        float mm = s_wred[0];
        for (int w = 1; w < 8; ++w) mm = fmaxf(mm, s_wred[w]);
        s_bcast = mm;
    }
    __syncthreads();
    const float zmax = s_bcast;

    // block sum of exp(z - zmax)
    float ssum = expf(z - zmax);
    #pragma unroll
    for (int off = 32; off > 0; off >>= 1)
        ssum += __shfl_down(ssum, off, 64);
    __syncthreads();              // everyone has read s_bcast; safe to reuse LDS
    if (lane == 0) s_wred[wave] = ssum;
    __syncthreads();
    if (tid == 0) {
        float tot = 0.0f;
        for (int w = 0; w < 8; ++w) tot += s_wred[w];
        s_bcast = logf(tot);
        ((unsigned int*)ws)[512] = 0x7F800000u;   // +inf bits: init loss slot
    }
    __syncthreads();
    const float lse = s_bcast;

    ws[tid] = z - zmax - lse;     // enc_j
}

__global__ __launch_bounds__(256) void k_dist_copy(
    const float* __restrict__ memory, const float* __restrict__ mem_data,
    float* __restrict__ out, const float* __restrict__ ws)
{
    __shared__ alignas(16) float s_enc[OUT_DIM];
    __shared__ float s_min[4];
    const int tid = threadIdx.x;
    const int lane = tid & 63;
    const int wave = tid >> 6;

    s_enc[tid] = ws[tid];
    s_enc[256 + tid] = ws[256 + tid];
    __syncthreads();

    const v4 e0 = ((const v4*)s_enc)[lane];
    const v4 e1 = ((const v4*)s_enc)[64 + lane];

    const int gwave = blockIdx.x * 4 + wave;     // 0..8191
    float wmin = INFINITY;
    float* const out_mem = out + 1;

    // Each wave owns a contiguous 16-row (32 KB) chunk: single-writer on all
    // interior misaligned boundary lines, contiguous DRAM footprint per wave.
    const int row0 = gwave * 16;
    #pragma unroll 2
    for (int rr = 0; rr < 16; ++rr) {
        const int r = row0 + rr;
        const v4* src = (const v4*)(memory + (size_t)r * OUT_DIM);
        const v4 a0 = __builtin_nontemporal_load(src + lane);
        const v4 a1 = __builtin_nontemporal_load(src + 64 + lane);

        float s = fabsf(a0[0] - e0[0]) + fabsf(a0[1] - e0[1])
                + fabsf(a0[2] - e0[2]) + fabsf(a0[3] - e0[3])
                + fabsf(a1[0] - e1[0]) + fabsf(a1[1] - e1[1])
                + fabsf(a1[2] - e1[2]) + fabsf(a1[3] - e1[3]);

        // fused copy: contiguous (unaligned) 16B nontemporal store per lane
        float* dst = out_mem + (size_t)r * OUT_DIM;
        __builtin_nontemporal_store((v4u)a0, (v4u*)(dst + 4 * lane));
        __builtin_nontemporal_store((v4u)a1, (v4u*)(dst + 256 + 4 * lane));

        #pragma unroll
        for (int off = 32; off > 0; off >>= 1)
            s += __shfl_down(s, off, 64);
        if (lane == 0) wmin = fminf(wmin, s);
    }

    if (lane == 0) s_min[wave] = wmin;
    __syncthreads();
    if (tid == 0) {
        float bm = fminf(fminf(s_min[0], s_min[1]), fminf(s_min[2], s_min[3]));
        atomicMin((unsigned int*)ws + 512, __float_as_uint(bm));
    }

    // mem_data copy: each wave owns a contiguous 16 KB span (1024 float4s),
    // lanes interleaved within, NT loads + contiguous unaligned NT stores.
    float* const out_md = out + 1 + (size_t)MEM_LEN * OUT_DIM;
    const v4* src4 = (const v4*)mem_data;
    const size_t base4 = (size_t)gwave * 1024 + lane;
    #pragma unroll 4
    for (int it = 0; it < 16; ++it) {
        const size_t i = base4 + (size_t)it * 64;
        const v4 v = __builtin_nontemporal_load(src4 + i);
        __builtin_nontemporal_store((v4u)v, (v4u*)(out_md + i * 4));
    }
}

__global__ __launch_bounds__(512) void k_finalize(
    const float* __restrict__ x, const int* __restrict__ count,
    float* __restrict__ out, const float* __restrict__ ws)
{
    const int tid = threadIdx.x;
    const float loss = __uint_as_float(((const unsigned int*)ws)[512]);
    if (tid == 0) out[0] = loss;
    if (loss <= BETA) {
        int pos = count[0] % MEM_LEN;
        if (pos < 0) pos += MEM_LEN;
        out[1 + (size_t)pos * OUT_DIM + tid] = ws[tid];
        if (tid < IN_DIM)
            out[1 + (size_t)MEM_LEN * OUT_DIM + (size_t)pos * IN_DIM + tid] = x[tid];
    }
}

extern "C" void kernel_launch(void* const* d_in, const int* in_sizes, int n_in,
                              void* d_out, int out_size, void* d_ws, size_t ws_size,
                              hipStream_t stream) {
    const float* x        = (const float*)d_in[0];
    const float* W_enc    = (const float*)d_in[1];
    const float* b_enc    = (const float*)d_in[2];
    const float* memory   = (const float*)d_in[3];
    const float* mem_data = (const float*)d_in[4];
    const float* mean     = (const float*)d_in[5];
    const float* stdv     = (const float*)d_in[6];
    const int*   count    = (const int*)d_in[7];
    float* out = (float*)d_out;
    float* ws  = (float*)d_ws;

    k_enc1<<<NSLICE, 512, 0, stream>>>(x, W_enc, mean, stdv, ws);
    k_enc2<<<1, 512, 0, stream>>>(b_enc, ws);
    k_dist_copy<<<2048, 256, 0, stream>>>(memory, mem_data, out, ws);
    k_finalize<<<1, 512, 0, stream>>>(x, count, out, ws);
}

// Round 3
// 648.851 us; speedup vs baseline: 1.0598x; 1.0198x over previous
//
#include <hip/hip_runtime.h>

#define MEM_LEN 131072
#define IN_DIM 256
#define OUT_DIM 512
#define BETA 1.0f
#define NSLICE 16
#define KSLICE (IN_DIM / NSLICE)   // 16 k-rows of W per slice block

typedef float v4 __attribute__((vector_size(16)));

// ws layout (floats):
//   [0..511]                      enc (log_softmax output)
//   [512]                         loss bits (uint, atomicMin)
//   [1024 .. 1024+NSLICE*512)     k-slice partial dot products

__global__ __launch_bounds__(512) void k_enc1(
    const float* __restrict__ x, const float* __restrict__ W,
    const float* __restrict__ mean, const float* __restrict__ stdv,
    float* __restrict__ ws)
{
    __shared__ float s_new[KSLICE];
    const int tid = threadIdx.x;
    const int b = blockIdx.x;
    const int k0 = b * KSLICE;

    if (tid < KSLICE) {
        const int k = k0 + tid;
        const float sd = stdv[k];
        s_new[tid] = (sd == 0.0f) ? 0.0f : (x[k] - mean[k]) / sd;
    }
    __syncthreads();

    float acc = 0.0f;
    #pragma unroll
    for (int kk = 0; kk < KSLICE; ++kk)
        acc = fmaf(s_new[kk], W[(size_t)(k0 + kk) * OUT_DIM + tid], acc);
    ws[1024 + b * OUT_DIM + tid] = acc;
}

__global__ __launch_bounds__(512) void k_enc2(
    const float* __restrict__ bias, float* __restrict__ ws)
{
    __shared__ float s_wred[8];
    __shared__ float s_bcast;
    const int tid = threadIdx.x;
    const int lane = tid & 63;
    const int wave = tid >> 6;

    float z = bias[tid];
    #pragma unroll
    for (int s = 0; s < NSLICE; ++s)
        z += ws[1024 + s * OUT_DIM + tid];

    // block max
    float m = z;
    #pragma unroll
    for (int off = 32; off > 0; off >>= 1)
        m = fmaxf(m, __shfl_down(m, off, 64));
    if (lane == 0) s_wred[wave] = m;
    __syncthreads();
    if (tid == 0) {
        float mm = s_wred[0];
        for (int w = 1; w < 8; ++w) mm = fmaxf(mm, s_wred[w]);
        s_bcast = mm;
    }
    __syncthreads();
    const float zmax = s_bcast;

    // block sum of exp(z - zmax)
    float ssum = expf(z - zmax);
    #pragma unroll
    for (int off = 32; off > 0; off >>= 1)
        ssum += __shfl_down(ssum, off, 64);
    __syncthreads();              // everyone has read s_bcast; safe to reuse LDS
    if (lane == 0) s_wred[wave] = ssum;
    __syncthreads();
    if (tid == 0) {
        float tot = 0.0f;
        for (int w = 0; w < 8; ++w) tot += s_wred[w];
        s_bcast = logf(tot);
        ((unsigned int*)ws)[512] = 0x7F800000u;   // +inf bits: init loss slot
    }
    __syncthreads();
    const float lse = s_bcast;

    ws[tid] = z - zmax - lse;     // enc_j
}

// Copy identity: out[a] = mem[a-1] across the whole shifted region. Each lane
// stores {prev_lane.w, own.xyz} at an ALIGNED 16B address (shfl_up shifts the
// data instead of misaligning the address). A wave-uniform scalar carries the
// last dword across iterations; chunk-leading carry is one broadcast load.
__global__ __launch_bounds__(256) void k_dist_copy(
    const float* __restrict__ memory, const float* __restrict__ mem_data,
    float* __restrict__ out, const float* __restrict__ ws)
{
    __shared__ alignas(16) float s_enc[OUT_DIM];
    __shared__ float s_min[4];
    const int tid = threadIdx.x;
    const int lane = tid & 63;
    const int wave = tid >> 6;

    s_enc[tid] = ws[tid];
    s_enc[256 + tid] = ws[256 + tid];
    __syncthreads();

    const v4 e0 = ((const v4*)s_enc)[lane];
    const v4 e1 = ((const v4*)s_enc)[64 + lane];

    const int gwave = blockIdx.x * 4 + wave;     // 0..8191
    float wmin = INFINITY;

    // ---- memory: distance + shifted copy, 16 contiguous rows per wave ----
    const int row0 = gwave * 16;
    // carry = mem[512*row0 - 1] (last dword of previous chunk's last row).
    // gwave 0 has no predecessor: its first store lands on out[0..3]; out[0]
    // gets garbage here and is overwritten by k_finalize (loss).
    float carry = (gwave == 0) ? 0.0f : memory[(size_t)row0 * OUT_DIM - 1];

    #pragma unroll 2
    for (int rr = 0; rr < 16; ++rr) {
        const int r = row0 + rr;
        const v4* src = (const v4*)(memory + (size_t)r * OUT_DIM);
        const v4 a0 = __builtin_nontemporal_load(src + lane);
        const v4 a1 = __builtin_nontemporal_load(src + 64 + lane);

        float s = fabsf(a0[0] - e0[0]) + fabsf(a0[1] - e0[1])
                + fabsf(a0[2] - e0[2]) + fabsf(a0[3] - e0[3])
                + fabsf(a1[0] - e1[0]) + fabsf(a1[1] - e1[1])
                + fabsf(a1[2] - e1[2]) + fabsf(a1[3] - e1[3]);

        // shifted, fully-aligned 16B stores
        const float m63 = __shfl(a0[3], 63);     // a0.w of lane 63
        float pw0 = __shfl_up(a0[3], 1);
        if (lane == 0) pw0 = carry;
        float pw1 = __shfl_up(a1[3], 1);
        if (lane == 0) pw1 = m63;
        carry = __shfl(a1[3], 63);               // next iteration's lead-in

        const v4 s0 = {pw0, a0[0], a0[1], a0[2]};
        const v4 s1 = {pw1, a1[0], a1[1], a1[2]};
        v4* dst = (v4*)(out + (size_t)r * OUT_DIM);   // absolute dword 512r: 16B-aligned
        __builtin_nontemporal_store(s0, dst + lane);
        __builtin_nontemporal_store(s1, dst + 64 + lane);

        #pragma unroll
        for (int off = 32; off > 0; off >>= 1)
            s += __shfl_down(s, off, 64);
        if (lane == 0) wmin = fminf(wmin, s);
    }

    if (lane == 0) s_min[wave] = wmin;
    __syncthreads();
    if (tid == 0) {
        float bm = fminf(fminf(s_min[0], s_min[1]), fminf(s_min[2], s_min[3]));
        atomicMin((unsigned int*)ws + 512, __float_as_uint(bm));
    }

    // ---- mem_data: shifted copy, 4096 contiguous dwords (1024 float4) per wave ----
    // First aligned group of this region is {mem[last], md[0..2]}: gwave 0's
    // carry is the last element of `memory` (the global carry-out above).
    float carry2 = (gwave == 0) ? memory[(size_t)MEM_LEN * OUT_DIM - 1]
                                : mem_data[(size_t)gwave * 4096 - 1];
    const v4* src4 = (const v4*)mem_data;
    v4* outA = (v4*)(out + (size_t)MEM_LEN * OUT_DIM);  // absolute dword 67108864: aligned
    const int base4 = gwave * 1024 + lane;
    #pragma unroll 4
    for (int it = 0; it < 16; ++it) {
        const int i = base4 + it * 64;
        const v4 v = __builtin_nontemporal_load(src4 + i);
        float pw = __shfl_up(v[3], 1);
        if (lane == 0) pw = carry2;
        carry2 = __shfl(v[3], 63);
        const v4 t = {pw, v[0], v[1], v[2]};
        __builtin_nontemporal_store(t, outA + i);
    }
    // global tail: the very last output dword = md[MEM_LEN*IN_DIM - 1]
    if (gwave == 8191 && lane == 0)
        out[(size_t)MEM_LEN * (OUT_DIM + IN_DIM)] = carry2;
}

__global__ __launch_bounds__(512) void k_finalize(
    const float* __restrict__ x, const int* __restrict__ count,
    float* __restrict__ out, const float* __restrict__ ws)
{
    const int tid = threadIdx.x;
    const float loss = __uint_as_float(((const unsigned int*)ws)[512]);
    if (tid == 0) out[0] = loss;   // also repairs the garbage dword from gwave 0
    if (loss <= BETA) {
        int pos = count[0] % MEM_LEN;
        if (pos < 0) pos += MEM_LEN;
        out[1 + (size_t)pos * OUT_DIM + tid] = ws[tid];
        if (tid < IN_DIM)
            out[1 + (size_t)MEM_LEN * OUT_DIM + (size_t)pos * IN_DIM + tid] = x[tid];
    }
}

extern "C" void kernel_launch(void* const* d_in, const int* in_sizes, int n_in,
                              void* d_out, int out_size, void* d_ws, size_t ws_size,
                              hipStream_t stream) {
    const float* x        = (const float*)d_in[0];
    const float* W_enc    = (const float*)d_in[1];
    const float* b_enc    = (const float*)d_in[2];
    const float* memory   = (const float*)d_in[3];
    const float* mem_data = (const float*)d_in[4];
    const float* mean     = (const float*)d_in[5];
    const float* stdv     = (const float*)d_in[6];
    const int*   count    = (const int*)d_in[7];
    float* out = (float*)d_out;
    float* ws  = (float*)d_ws;

    k_enc1<<<NSLICE, 512, 0, stream>>>(x, W_enc, mean, stdv, ws);
    k_enc2<<<1, 512, 0, stream>>>(b_enc, ws);
    k_dist_copy<<<2048, 256, 0, stream>>>(memory, mem_data, out, ws);
    k_finalize<<<1, 512, 0, stream>>>(x, count, out, ws);
}